// Round 5
// baseline (798.622 us; speedup 1.0000x reference)
//
#include <hip/hip_runtime.h>
#include <hip/hip_cooperative_groups.h>
#include <math.h>

namespace cg = cooperative_groups;

#define S_LEN 2048
#define E_DIM 512
#define NE (S_LEN * E_DIM)
#define NOFF 65
#define PROW 520
#define PN (S_LEN * PROW)

typedef float f32x4 __attribute__((ext_vector_type(4)));
typedef short short8 __attribute__((ext_vector_type(8)));

__device__ __forceinline__ unsigned short f2bf(float f) {
    union { float f; unsigned u; } cv; cv.f = f;
    unsigned u = cv.u;
    u += 0x7fffu + ((u >> 16) & 1u);   // RNE
    return (unsigned short)(u >> 16);
}
__device__ __forceinline__ unsigned pk2(float x, float y) {
    return (unsigned)f2bf(x) | ((unsigned)f2bf(y) << 16);
}

// ===========================================================================
// Phase bodies — shared between the fused cooperative kernel and the
// discrete-launch fallback. All are 512-thread bodies.
// ===========================================================================

// ---- GEMM tile: one 64x64 out tile of (x @ W{q,k,v} + b)*scale. 8 waves,
// each 16(m)x32(n) via 2 MFMA 16x16x32 accumulators. BK=32, fp32->bf16 in
// staging (B via column-gather, coalesced along n). smem: 10240 B.
__device__ __forceinline__ void gemm_tile(char* smem, int tile,
    const float* __restrict__ x,
    const float* __restrict__ Wq, const float* __restrict__ bq,
    const float* __restrict__ Wk, const float* __restrict__ bk,
    const float* __restrict__ Wv, const float* __restrict__ bv,
    float* __restrict__ q, float* __restrict__ kb, float* __restrict__ v)
{
    unsigned short* As = (unsigned short*)smem;            // 64*40*2 = 5120
    unsigned short* Bs = (unsigned short*)(smem + 5120);   // 64*40*2 = 5120
    const int tid = threadIdx.x;
    const int z = tile >> 8, rem = tile & 255;
    const int n0 = (rem & 7) * 64, m0 = (rem >> 3) * 64;
    const float* W    = (z == 0) ? Wq : (z == 1) ? Wk : Wv;
    const float* bias = (z == 0) ? bq : (z == 1) ? bk : bv;
    float* C          = (z == 0) ? q  : (z == 1) ? kb : v;
    const float scale = (z == 0) ? 0.125f : 1.0f;

    const int lane = tid & 63, wave = tid >> 6;
    const int quad = lane >> 4, l16 = lane & 15;
    const int wm = (wave & 3) * 16, wn = (wave >> 2) * 32;
    const int ar = tid >> 3, ac = (tid & 7) * 4;       // A: 64 rows x 32 k
    const int bn = tid & 63, bk0 = (tid >> 6) * 4;     // B: 64 n x 32 k

    f32x4 acc0 = {0.f,0.f,0.f,0.f}, acc1 = acc0;

    for (int kk = 0; kk < E_DIM; kk += 32) {
        float4 av = *(const float4*)(x + (size_t)(m0 + ar) * E_DIM + kk + ac);
        float b0 = W[(size_t)(kk + bk0 + 0) * E_DIM + n0 + bn];
        float b1 = W[(size_t)(kk + bk0 + 1) * E_DIM + n0 + bn];
        float b2 = W[(size_t)(kk + bk0 + 2) * E_DIM + n0 + bn];
        float b3 = W[(size_t)(kk + bk0 + 3) * E_DIM + n0 + bn];
        __syncthreads();   // previous iter's fragment reads done
        uint2 ap; ap.x = pk2(av.x, av.y); ap.y = pk2(av.z, av.w);
        *(uint2*)(As + ar * 40 + ac) = ap;
        uint2 bp; bp.x = pk2(b0, b1); bp.y = pk2(b2, b3);
        *(uint2*)(Bs + bn * 40 + bk0) = bp;
        __syncthreads();
        short8 fa  = *(const short8*)(As + (wm + l16) * 40 + quad * 8);
        short8 fb0 = *(const short8*)(Bs + (wn + l16) * 40 + quad * 8);
        short8 fb1 = *(const short8*)(Bs + (wn + 16 + l16) * 40 + quad * 8);
        acc0 = __builtin_amdgcn_mfma_f32_16x16x32_bf16(fa, fb0, acc0, 0, 0, 0);
        acc1 = __builtin_amdgcn_mfma_f32_16x16x32_bf16(fa, fb1, acc1, 0, 0, 0);
    }

    // C/D layout: col = lane&15, row = quad*4 + reg
#pragma unroll
    for (int ni = 0; ni < 2; ++ni) {
        f32x4 a = ni ? acc1 : acc0;
        int n = n0 + wn + ni * 16 + l16;
        float bval = bias[n];
#pragma unroll
        for (int r = 0; r < 4; ++r) {
            int m = m0 + wm + quad * 4 + r;
            C[(size_t)m * E_DIM + n] = (a[r] + bval) * scale;
        }
    }
}

// ---- scores: unit b = 64 dst rows x 1 head. smem: 52736 B.
// P[i][h][off] with exact zeros for nonexistent edges.
__device__ __forceinline__ void scores_body(char* smem, int b,
    const float* __restrict__ q, const float* __restrict__ kb,
    const float* __restrict__ amask, float* __restrict__ P)
{
    float* ks   = (float*)smem;            // 128*68*4 = 34816
    float* am   = (float*)(smem + 34816);  // 512
    float* sc   = (float*)(smem + 35328);  // 64*66*4 = 16896
    float* smx  = (float*)(smem + 52224);  // 256
    float* sidn = (float*)(smem + 52480);  // 256 (end 52736)
    const int tid = threadIdx.x;
    const int i0 = (b & 31) * 64;
    const int h  = b >> 5;

    for (int e = tid; e < 128 * 16; e += 512) {
        int lr = e >> 4, c4 = e & 15;
        int j = i0 - 32 + lr;
        int jc = min(max(j, 0), S_LEN - 1);
        *(float4*)(ks + lr * 68 + c4 * 4) =
            *(const float4*)(kb + (size_t)jc * E_DIM + h * 64 + c4 * 4);
    }
    if (tid < 128) {
        int j = i0 - 32 + tid;
        am[tid] = (j >= 0 && j < S_LEN) ? amask[j] : -1.0f;
    }

    const int dst = tid >> 3;          // 64 dst
    const int og  = tid & 7;           // 8 off-groups
    float4 qreg[16];
    {
        const float4* qrow = (const float4*)(q + (size_t)(i0 + dst) * E_DIM + h * 64);
#pragma unroll
        for (int t = 0; t < 16; ++t) qreg[t] = qrow[t];
    }
    __syncthreads();

    for (int off = og; off < NOFF; off += 8) {
        int j = i0 + dst + off - 32;
        float s;
        if (j < 0 || j >= S_LEN) {
            s = -INFINITY;
        } else {
            int lr = dst + off;
            const float4* kr = (const float4*)(ks + lr * 68);
            float acc = 0.f;
#pragma unroll
            for (int t = 0; t < 16; ++t) {
                float4 a = qreg[t], bb = kr[t];
                acc += a.x * bb.x + a.y * bb.y + a.z * bb.z + a.w * bb.w;
            }
            s = (am[lr] >= 0.f) ? acc : -1e9f;
        }
        sc[dst * 66 + off] = s;
    }
    __syncthreads();

    if (tid < 64) {
        float mx = -INFINITY;
        for (int o = 0; o < NOFF; ++o) mx = fmaxf(mx, sc[tid * 66 + o]);
        float dn = 0.f;
        for (int o = 0; o < NOFF; ++o) dn += expf(sc[tid * 66 + o] - mx);
        smx[tid] = mx; sidn[tid] = 1.f / dn;
    }
    __syncthreads();

    for (int e = tid; e < 64 * NOFF; e += 512) {
        int d = e / NOFF, off = e - d * NOFF;
        float pv = expf(sc[d * 66 + off] - smx[d]) * sidn[d];
        P[(size_t)(i0 + d) * PROW + h * NOFF + off] = pv;
    }
}

// ---- one diffusion step: unit b = 64 out rows x 1 head. No recompute —
// halo comes fresh from global. smem: 51456 B.
__device__ __forceinline__ void diffuse_body(char* smem, int b,
    const float* __restrict__ hin, const float* __restrict__ v,
    const float* __restrict__ P, float* __restrict__ hout)
{
    float* hs = (float*)smem;             // 128*68*4 = 34816
    float* ps = (float*)(smem + 34816);   // 64*65*4 = 16640 (end 51456)
    const int tid = threadIdx.x;
    const int i0 = (b & 31) * 64;
    const int h  = b >> 5;

    for (int e = tid; e < 128 * 16; e += 512) {
        int lr = e >> 4, c4 = e & 15;
        int j = i0 - 32 + lr;
        int jc = min(max(j, 0), S_LEN - 1);   // P==0 off-band, clamp safe
        *(float4*)(hs + lr * 68 + c4 * 4) =
            *(const float4*)(hin + (size_t)jc * E_DIM + h * 64 + c4 * 4);
    }
    for (int e = tid; e < 64 * NOFF; e += 512) {
        int r = e / NOFF, o = e - r * NOFF;
        ps[e] = P[(size_t)(i0 + r) * PROW + h * NOFF + o];
    }
    __syncthreads();

    const int ci = tid & 15;           // float4 col
    const int ob = (tid >> 4) * 2;     // 2 out rows per thread
    float4 a0 = {0,0,0,0}, a1 = a0;
    for (int lr = ob; lr < ob + 66; ++lr) {
        float4 hval = *(const float4*)(hs + lr * 68 + ci * 4);
        int o0 = lr - ob;
        if (o0 <= 64) {
            float p = ps[ob * NOFF + o0];
            a0.x += p * hval.x; a0.y += p * hval.y; a0.z += p * hval.z; a0.w += p * hval.w;
        }
        int o1 = o0 - 1;
        if ((unsigned)o1 <= 64u) {
            float p = ps[(ob + 1) * NOFF + o1];
            a1.x += p * hval.x; a1.y += p * hval.y; a1.z += p * hval.z; a1.w += p * hval.w;
        }
    }
#pragma unroll
    for (int r = 0; r < 2; ++r) {
        float4 a = r ? a1 : a0;
        size_t base = (size_t)(i0 + ob + r) * E_DIM + h * 64 + ci * 4;
        float4 vv = *(const float4*)(v + base);
        float4 o;
        o.x = 0.9f * a.x + 0.1f * vv.x;
        o.y = 0.9f * a.y + 0.1f * vv.y;
        o.z = 0.9f * a.z + 0.1f * vv.z;
        o.w = 0.9f * a.w + 0.1f * vv.w;
        *(float4*)(hout + base) = o;
    }
}

// ---- oln: 16 rows x 512 cols per unit (b in 0..127), fused GEMM+resid+LN.
// smem: 43264 B. Proven in round 4.
__device__ __forceinline__ void oln_body(char* smem, int b,
    const float* __restrict__ hsrc, const float* __restrict__ Wo,
    const float* __restrict__ bo, const float* __restrict__ x,
    const float* __restrict__ g, const float* __restrict__ lb,
    float* __restrict__ out)
{
    unsigned short* As = (unsigned short*)smem;            // 16*40*2 = 1280
    unsigned short* Bs = (unsigned short*)(smem + 1280);   // 512*40*2 = 40960
    float* rsum = (float*)(smem + 42240);                  // 8*16*4 = 512
    float* rsq  = (float*)(smem + 42752);                  // 512 (end 43264)
    const int tid = threadIdx.x;
    const int lane = tid & 63, wave = tid >> 6;
    const int quad = lane >> 4, l16 = lane & 15;
    const int m0 = b * 16;
    const int n = tid;

    f32x4 acc[4];
#pragma unroll
    for (int t = 0; t < 4; ++t) acc[t] = (f32x4){0.f,0.f,0.f,0.f};

    for (int kk = 0; kk < E_DIM; kk += 32) {
        float4 av;
        if (tid < 128)
            av = *(const float4*)(hsrc + (size_t)(m0 + (tid >> 3)) * E_DIM + kk + (tid & 7) * 4);
        float bcol[32];
#pragma unroll
        for (int j = 0; j < 32; ++j)
            bcol[j] = Wo[(size_t)(kk + j) * E_DIM + n];
        __syncthreads();
        if (tid < 128) {
            uint2 ap; ap.x = pk2(av.x, av.y); ap.y = pk2(av.z, av.w);
            *(uint2*)(As + (tid >> 3) * 40 + (tid & 7) * 4) = ap;
        }
#pragma unroll
        for (int t = 0; t < 4; ++t) {
            uint4 bp;
            bp.x = pk2(bcol[t*8+0], bcol[t*8+1]); bp.y = pk2(bcol[t*8+2], bcol[t*8+3]);
            bp.z = pk2(bcol[t*8+4], bcol[t*8+5]); bp.w = pk2(bcol[t*8+6], bcol[t*8+7]);
            *(uint4*)(Bs + n * 40 + t * 8) = bp;
        }
        __syncthreads();
        short8 fa = *(const short8*)(As + l16 * 40 + quad * 8);
#pragma unroll
        for (int nt = 0; nt < 4; ++nt) {
            short8 fb = *(const short8*)(Bs + (wave * 64 + nt * 16 + l16) * 40 + quad * 8);
            acc[nt] = __builtin_amdgcn_mfma_f32_16x16x32_bf16(fa, fb, acc[nt], 0, 0, 0);
        }
    }

    float s[4] = {0.f,0.f,0.f,0.f}, s2[4] = {0.f,0.f,0.f,0.f};
#pragma unroll
    for (int nt = 0; nt < 4; ++nt) {
        int nc = wave * 64 + nt * 16 + l16;
        float bv = bo[nc];
#pragma unroll
        for (int r = 0; r < 4; ++r) {
            int m = m0 + quad * 4 + r;
            float vl = acc[nt][r] + bv + x[(size_t)m * E_DIM + nc];
            acc[nt][r] = vl;
            s[r] += vl; s2[r] += vl * vl;
        }
    }
#pragma unroll
    for (int o = 1; o < 16; o <<= 1) {
#pragma unroll
        for (int r = 0; r < 4; ++r) {
            s[r]  += __shfl_xor(s[r], o, 64);
            s2[r] += __shfl_xor(s2[r], o, 64);
        }
    }
    if (l16 == 0) {
#pragma unroll
        for (int r = 0; r < 4; ++r) {
            rsum[wave * 16 + quad * 4 + r] = s[r];
            rsq[wave * 16 + quad * 4 + r]  = s2[r];
        }
    }
    __syncthreads();
    float mu[4], rs[4];
#pragma unroll
    for (int r = 0; r < 4; ++r) {
        int rl = quad * 4 + r;
        float tot = 0.f, tot2 = 0.f;
#pragma unroll
        for (int w = 0; w < 8; ++w) { tot += rsum[w * 16 + rl]; tot2 += rsq[w * 16 + rl]; }
        float m_ = tot * (1.f / 512.f);
        float var = tot2 * (1.f / 512.f) - m_ * m_;
        mu[r] = m_; rs[r] = rsqrtf(var + 1e-12f);
    }
#pragma unroll
    for (int nt = 0; nt < 4; ++nt) {
        int nc = wave * 64 + nt * 16 + l16;
        float gv = g[nc], bbv = lb[nc];
#pragma unroll
        for (int r = 0; r < 4; ++r) {
            int m = m0 + quad * 4 + r;
            out[(size_t)m * E_DIM + nc] = (acc[nt][r] - mu[r]) * rs[r] * gv + bbv;
        }
    }
}

// ===========================================================================
// Fused cooperative kernel: 256 blocks x 512 threads, grid.sync() between
// phases. Eliminates 5 inter-dispatch gaps and all diffusion recompute.
// ===========================================================================
__global__ __launch_bounds__(512, 1)
void fused(const float* __restrict__ x, const float* __restrict__ amask,
           const float* __restrict__ Wq, const float* __restrict__ bq,
           const float* __restrict__ Wk, const float* __restrict__ bk,
           const float* __restrict__ Wv, const float* __restrict__ bv,
           const float* __restrict__ Wo, const float* __restrict__ bo,
           const float* __restrict__ lng, const float* __restrict__ lnb,
           float* __restrict__ out,
           float* __restrict__ q, float* __restrict__ kb, float* __restrict__ v,
           float* __restrict__ P, float* __restrict__ hA, float* __restrict__ hB)
{
    __shared__ __align__(16) char smem[53248];
    cg::grid_group grid = cg::this_grid();
    const int b = blockIdx.x;

    // P1: QKV — 768 tiles, 3 per block
    for (int t = 0; t < 3; ++t)
        gemm_tile(smem, b + t * 256, x, Wq, bq, Wk, bk, Wv, bv, q, kb, v);
    __threadfence(); grid.sync();

    // P2: scores + edge softmax
    scores_body(smem, b, q, kb, amask, P);
    __threadfence(); grid.sync();

    // P3-P7: five diffusion steps, halo through L2 + grid barrier
    diffuse_body(smem, b, v,  v, P, hA); __threadfence(); grid.sync();
    diffuse_body(smem, b, hA, v, P, hB); __threadfence(); grid.sync();
    diffuse_body(smem, b, hB, v, P, hA); __threadfence(); grid.sync();
    diffuse_body(smem, b, hA, v, P, hB); __threadfence(); grid.sync();
    diffuse_body(smem, b, hB, v, P, hA); __threadfence(); grid.sync();

    // P8: output GEMM + residual + LayerNorm (blocks 0..127)
    if (b < 128)
        oln_body(smem, b, hA, Wo, bo, x, lng, lnb, out);
}

// ===========================================================================
// Discrete-launch fallback (if cooperative launch is rejected)
// ===========================================================================
__global__ __launch_bounds__(512, 1)
void k_qkv(const float* x, const float* Wq, const float* bq,
           const float* Wk, const float* bk, const float* Wv, const float* bv,
           float* q, float* kb, float* v)
{
    __shared__ __align__(16) char smem[10240];
    gemm_tile(smem, blockIdx.x, x, Wq, bq, Wk, bk, Wv, bv, q, kb, v);
}

__global__ __launch_bounds__(512, 1)
void k_scores(const float* q, const float* kb, const float* amask, float* P)
{
    __shared__ __align__(16) char smem[53248];
    scores_body(smem, blockIdx.x, q, kb, amask, P);
}

__global__ __launch_bounds__(512, 1)
void k_diffuse(const float* hin, const float* v, const float* P, float* hout)
{
    __shared__ __align__(16) char smem[51456];
    diffuse_body(smem, blockIdx.x, hin, v, P, hout);
}

__global__ __launch_bounds__(512, 1)
void k_oln(const float* hsrc, const float* Wo, const float* bo, const float* x,
           const float* g, const float* lb, float* out)
{
    __shared__ __align__(16) char smem[43264];
    oln_body(smem, blockIdx.x, hsrc, Wo, bo, x, g, lb, out);
}

// ===========================================================================
extern "C" void kernel_launch(void* const* d_in, const int* in_sizes, int n_in,
                              void* d_out, int out_size, void* d_ws, size_t ws_size,
                              hipStream_t stream)
{
    const float* x     = (const float*)d_in[0];
    const float* amask = (const float*)d_in[1];
    const float* Wq = (const float*)d_in[4];
    const float* bq = (const float*)d_in[5];
    const float* Wk = (const float*)d_in[6];
    const float* bk = (const float*)d_in[7];
    const float* Wv = (const float*)d_in[8];
    const float* bv = (const float*)d_in[9];
    const float* Wo = (const float*)d_in[10];
    const float* bo = (const float*)d_in[11];
    const float* lng = (const float*)d_in[12];
    const float* lnb = (const float*)d_in[13];
    float* out = (float*)d_out;

    float* ws = (float*)d_ws;
    float* q  = ws;
    float* kb = ws + (size_t)NE;
    float* v  = ws + (size_t)2 * NE;
    float* P  = ws + (size_t)3 * NE;
    float* hA = ws + (size_t)3 * NE + PN;
    float* hB = hA + (size_t)NE;

    void* args[] = { (void*)&x, (void*)&amask,
                     (void*)&Wq, (void*)&bq, (void*)&Wk, (void*)&bk,
                     (void*)&Wv, (void*)&bv, (void*)&Wo, (void*)&bo,
                     (void*)&lng, (void*)&lnb, (void*)&out,
                     (void*)&q, (void*)&kb, (void*)&v, (void*)&P,
                     (void*)&hA, (void*)&hB };

    hipError_t rc = hipLaunchCooperativeKernel((void*)fused, dim3(256), dim3(512),
                                               args, 0, stream);
    if (rc != hipSuccess) {
        (void)hipGetLastError();   // clear sticky error, use discrete path
        k_qkv<<<768, 512, 0, stream>>>(x, Wq, bq, Wk, bk, Wv, bv, q, kb, v);
        k_scores<<<256, 512, 0, stream>>>(q, kb, amask, P);
        k_diffuse<<<256, 512, 0, stream>>>(v,  v, P, hA);
        k_diffuse<<<256, 512, 0, stream>>>(hA, v, P, hB);
        k_diffuse<<<256, 512, 0, stream>>>(hB, v, P, hA);
        k_diffuse<<<256, 512, 0, stream>>>(hA, v, P, hB);
        k_diffuse<<<256, 512, 0, stream>>>(hB, v, P, hA);
        k_oln<<<128, 512, 0, stream>>>(hA, Wo, bo, x, lng, lnb, out);
    }
}

// Round 6
// 183.731 us; speedup vs baseline: 4.3467x; 4.3467x over previous
//
#include <hip/hip_runtime.h>
#include <math.h>

#define S_LEN 2048
#define E_DIM 512
#define NE (S_LEN * E_DIM)
#define H_NUM 8
#define WH 32
#define NOFF 65
#define PROW (H_NUM * NOFF) /* 520 */
#define PN (S_LEN * PROW)

typedef float f32x4 __attribute__((ext_vector_type(4)));
typedef short short8 __attribute__((ext_vector_type(8)));

__device__ __forceinline__ unsigned short f2bf(float f) {
    union { float f; unsigned u; } cv; cv.f = f;
    unsigned u = cv.u;
    u += 0x7fffu + ((u >> 16) & 1u);   // RNE
    return (unsigned short)(u >> 16);
}
__device__ __forceinline__ unsigned pk2(float x, float y) {
    return (unsigned)f2bf(x) | ((unsigned)f2bf(y) << 16);
}

// ---------------------------------------------------------------------------
// qkv: C = (x@W + bias)*scale from fp32 x and fp32 W (row-major [k][n]).
// In-kernel cast to bf16; B staged via column-gather, stored [n][k] in LDS.
// Tile 64x64, 4 waves, 2x2 MFMA 16x16x32. (proven R3)
// ---------------------------------------------------------------------------
__device__ __forceinline__ void mfma_gemm_f32(
    const float* __restrict__ A, const float* __restrict__ W,
    const float* __restrict__ bias, float* __restrict__ C,
    float scale, int m0, int n0)
{
    __shared__ unsigned short As[64 * 40];  // [m][k] pad 40
    __shared__ unsigned short Bs[64 * 40];  // [n][k] pad 40
    const int tid = threadIdx.x;
    const int lane = tid & 63, wave = tid >> 6;
    const int quad = lane >> 4, l16 = lane & 15;
    const int wr = (wave >> 1) * 32, wc = (wave & 1) * 32;
    const int ar = tid >> 2, ac = (tid & 3) * 8;      // A: row, k-chunk
    const int bn = tid & 63, bk0 = (tid >> 6) * 8;    // B: n-col, k-group

    f32x4 acc00 = {0.f,0.f,0.f,0.f}, acc01 = acc00, acc10 = acc00, acc11 = acc00;

    for (int kk = 0; kk < E_DIM; kk += 32) {
        float4 a0 = *(const float4*)(A + (size_t)(m0 + ar) * E_DIM + kk + ac);
        float4 a1 = *(const float4*)(A + (size_t)(m0 + ar) * E_DIM + kk + ac + 4);
        float b[8];
#pragma unroll
        for (int j = 0; j < 8; ++j)
            b[j] = W[(size_t)(kk + bk0 + j) * E_DIM + n0 + bn];
        __syncthreads();   // previous iter's fragment reads done
        uint4 ap; ap.x = pk2(a0.x, a0.y); ap.y = pk2(a0.z, a0.w);
        ap.z = pk2(a1.x, a1.y); ap.w = pk2(a1.z, a1.w);
        *(uint4*)(As + ar * 40 + ac) = ap;
        uint4 bp; bp.x = pk2(b[0], b[1]); bp.y = pk2(b[2], b[3]);
        bp.z = pk2(b[4], b[5]); bp.w = pk2(b[6], b[7]);
        *(uint4*)(Bs + bn * 40 + bk0) = bp;
        __syncthreads();
        short8 fa0 = *(const short8*)(As + (wr + l16) * 40 + quad * 8);
        short8 fa1 = *(const short8*)(As + (wr + 16 + l16) * 40 + quad * 8);
        short8 fb0 = *(const short8*)(Bs + (wc + l16) * 40 + quad * 8);
        short8 fb1 = *(const short8*)(Bs + (wc + 16 + l16) * 40 + quad * 8);
        acc00 = __builtin_amdgcn_mfma_f32_16x16x32_bf16(fa0, fb0, acc00, 0, 0, 0);
        acc01 = __builtin_amdgcn_mfma_f32_16x16x32_bf16(fa0, fb1, acc01, 0, 0, 0);
        acc10 = __builtin_amdgcn_mfma_f32_16x16x32_bf16(fa1, fb0, acc10, 0, 0, 0);
        acc11 = __builtin_amdgcn_mfma_f32_16x16x32_bf16(fa1, fb1, acc11, 0, 0, 0);
    }

    // C/D layout: col = lane&15, row = quad*4 + reg
#pragma unroll
    for (int mi = 0; mi < 2; ++mi) {
#pragma unroll
        for (int ni = 0; ni < 2; ++ni) {
            f32x4 a = (mi == 0) ? ((ni == 0) ? acc00 : acc01)
                                : ((ni == 0) ? acc10 : acc11);
            int n = n0 + wc + ni * 16 + l16;
            float bval = bias[n];
#pragma unroll
            for (int r = 0; r < 4; ++r) {
                int m = m0 + wr + mi * 16 + quad * 4 + r;
                C[(size_t)m * E_DIM + n] = (a[r] + bval) * scale;
            }
        }
    }
}

__global__ __launch_bounds__(256)
void qkv_gemm(const float* __restrict__ x,
              const float* __restrict__ Wq, const float* __restrict__ bq,
              const float* __restrict__ Wk, const float* __restrict__ bk,
              const float* __restrict__ Wv, const float* __restrict__ bv,
              float* __restrict__ q, float* __restrict__ k, float* __restrict__ v)
{
    const float* W; const float* b; float* o; float sc;
    if (blockIdx.z == 0)      { W = Wq; b = bq; o = q; sc = 0.125f; }
    else if (blockIdx.z == 1) { W = Wk; b = bk; o = k; sc = 1.0f; }
    else                      { W = Wv; b = bv; o = v; sc = 1.0f; }
    mfma_gemm_f32(x, W, b, o, sc, blockIdx.y * 64, blockIdx.x * 64);
}

// ---------------------------------------------------------------------------
// scores: block = 32 dst x 1 head (512 blocks). P has exact zeros off-band.
// (proven R3)
// ---------------------------------------------------------------------------
#define SDN 32
__global__ __launch_bounds__(256)
void scores_kernel(const float* __restrict__ q, const float* __restrict__ k,
                   const float* __restrict__ amask, float* __restrict__ P)
{
    const int i0 = blockIdx.x * SDN;
    const int h  = blockIdx.y;
    const int tid = threadIdx.x;
    __shared__ float ks[96 * 68];
    __shared__ float am[96];
    __shared__ float sc[SDN * 66];     // [dst][off]
    __shared__ float smx[SDN], sidn[SDN];

    for (int e = tid; e < 96 * 16; e += 256) {
        int lr = e >> 4, c4 = e & 15;
        int j = i0 - WH + lr;
        int jc = min(max(j, 0), S_LEN - 1);
        *(float4*)(ks + lr * 68 + c4 * 4) =
            *(const float4*)(k + (size_t)jc * E_DIM + h * 64 + c4 * 4);
    }
    if (tid < 96) {
        int j = i0 - WH + tid;
        am[tid] = (j >= 0 && j < S_LEN) ? amask[j] : -1.0f;
    }

    const int dst = tid >> 3;          // 32 dst
    const int og  = tid & 7;           // 8 off-groups
    float4 qreg[16];
    {
        const float4* qrow = (const float4*)(q + (size_t)(i0 + dst) * E_DIM + h * 64);
#pragma unroll
        for (int t = 0; t < 16; ++t) qreg[t] = qrow[t];
    }
    __syncthreads();

    for (int off = og; off < NOFF; off += 8) {
        int j = i0 + dst + off - WH;
        float s;
        if (j < 0 || j >= S_LEN) {
            s = -INFINITY;
        } else {
            int lr = dst + off;
            const float4* kr = (const float4*)(ks + lr * 68);
            float acc = 0.f;
#pragma unroll
            for (int t = 0; t < 16; ++t) {
                float4 a = qreg[t], bb = kr[t];
                acc += a.x * bb.x + a.y * bb.y + a.z * bb.z + a.w * bb.w;
            }
            s = (am[lr] >= 0.f) ? acc : -1e9f;
        }
        sc[dst * 66 + off] = s;
    }
    __syncthreads();

    if (tid < SDN) {
        float mx = -INFINITY;
        for (int o = 0; o < NOFF; ++o) mx = fmaxf(mx, sc[tid * 66 + o]);
        float dn = 0.f;
        for (int o = 0; o < NOFF; ++o) dn += expf(sc[tid * 66 + o] - mx);
        smx[tid] = mx; sidn[tid] = 1.f / dn;
    }
    __syncthreads();

    for (int e = tid; e < SDN * NOFF; e += 256) {
        int d = e / NOFF, off = e - d * NOFF;
        float pv = expf(sc[d * 66 + off] - smx[d]) * sidn[d];
        P[(size_t)(i0 + d) * PROW + h * NOFF + off] = pv;
    }
}

// ---------------------------------------------------------------------------
// diffuse2: TWO diffusion steps (halo recompute), proven R3.
// block = 64 out-nodes x 64 cols. in rows 192, mid rows 128 in LDS.
// ---------------------------------------------------------------------------
__global__ __launch_bounds__(512)
void diffuse2(const float* __restrict__ hin, const float* __restrict__ v,
              const float* __restrict__ P, float* __restrict__ hout)
{
    const int i0 = blockIdx.x * 64;
    const int h  = blockIdx.y;
    const int tid = threadIdx.x;
    __shared__ float hs[192 * 64];     // in rows  [i0-64, i0+128)
    __shared__ float h1[128 * 64];     // mid rows [i0-32, i0+96)
    __shared__ float ps[128 * NOFF];   // P for mid rows

    for (int e = tid; e < 192 * 16; e += 512) {
        int lr = e >> 4, c4 = e & 15;
        int j = i0 - 64 + lr;
        int jc = min(max(j, 0), S_LEN - 1);
        *(float4*)(hs + lr * 64 + c4 * 4) =
            *(const float4*)(hin + (size_t)jc * E_DIM + h * 64 + c4 * 4);
    }
    for (int e = tid; e < 128 * NOFF; e += 512) {
        int mr = e / NOFF, o = e - mr * NOFF;
        int j = i0 - 32 + mr;
        int jc = min(max(j, 0), S_LEN - 1);
        ps[e] = P[(size_t)jc * PROW + h * NOFF + o];
    }
    __syncthreads();

    const int c4 = (tid & 15) * 4;
    const int g  = tid >> 4;           // 32 groups x 4 mid-rows
    const float4* h4 = (const float4*)hs;
    const int ci = tid & 15;

    // ---- step A: mid rows g*4 .. g*4+3 ----
    {
        float4 a0 = {0,0,0,0}, a1 = a0, a2 = a0, a3 = a0;
        const int mb = g * 4;
        for (int lr = mb; lr < mb + 68; ++lr) {
            float4 hval = h4[lr * 16 + ci];
            int o0 = lr - mb;
            if ((unsigned)o0 <= 64u) {
                float p = ps[(mb + 0) * NOFF + o0];
                a0.x += p * hval.x; a0.y += p * hval.y; a0.z += p * hval.z; a0.w += p * hval.w;
            }
            int o1 = o0 - 1;
            if ((unsigned)o1 <= 64u) {
                float p = ps[(mb + 1) * NOFF + o1];
                a1.x += p * hval.x; a1.y += p * hval.y; a1.z += p * hval.z; a1.w += p * hval.w;
            }
            int o2 = o0 - 2;
            if ((unsigned)o2 <= 64u) {
                float p = ps[(mb + 2) * NOFF + o2];
                a2.x += p * hval.x; a2.y += p * hval.y; a2.z += p * hval.z; a2.w += p * hval.w;
            }
            int o3 = o0 - 3;
            if ((unsigned)o3 <= 64u) {
                float p = ps[(mb + 3) * NOFF + o3];
                a3.x += p * hval.x; a3.y += p * hval.y; a3.z += p * hval.z; a3.w += p * hval.w;
            }
        }
#pragma unroll
        for (int r = 0; r < 4; ++r) {
            float4 a = (r == 0) ? a0 : (r == 1) ? a1 : (r == 2) ? a2 : a3;
            int j = i0 - 32 + mb + r;
            int jc = min(max(j, 0), S_LEN - 1);
            float4 vv = *(const float4*)(v + (size_t)jc * E_DIM + h * 64 + c4);
            float4 o;
            o.x = 0.9f * a.x + 0.1f * vv.x;
            o.y = 0.9f * a.y + 0.1f * vv.y;
            o.z = 0.9f * a.z + 0.1f * vv.z;
            o.w = 0.9f * a.w + 0.1f * vv.w;
            *(float4*)(h1 + (mb + r) * 64 + c4) = o;
        }
    }
    __syncthreads();

    // ---- step B: out rows g*2 .. g*2+1 ----
    {
        const int ob = g * 2;
        const float4* m4 = (const float4*)h1;
        float4 a0 = {0,0,0,0}, a1 = a0;
        for (int lr = ob; lr < ob + 66; ++lr) {
            float4 hval = m4[lr * 16 + ci];
            int o0 = lr - ob;
            if ((unsigned)o0 <= 64u) {
                float p = ps[(ob + 32) * NOFF + o0];
                a0.x += p * hval.x; a0.y += p * hval.y; a0.z += p * hval.z; a0.w += p * hval.w;
            }
            int o1 = o0 - 1;
            if ((unsigned)o1 <= 64u) {
                float p = ps[(ob + 33) * NOFF + o1];
                a1.x += p * hval.x; a1.y += p * hval.y; a1.z += p * hval.z; a1.w += p * hval.w;
            }
        }
#pragma unroll
        for (int r = 0; r < 2; ++r) {
            float4 a = (r == 0) ? a0 : a1;
            size_t base = (size_t)(i0 + ob + r) * E_DIM + h * 64 + c4;
            float4 vv = *(const float4*)(v + base);
            float4 o;
            o.x = 0.9f * a.x + 0.1f * vv.x;
            o.y = 0.9f * a.y + 0.1f * vv.y;
            o.z = 0.9f * a.z + 0.1f * vv.z;
            o.w = 0.9f * a.w + 0.1f * vv.w;
            *(float4*)(hout + base) = o;
        }
    }
}

// ---------------------------------------------------------------------------
// diffuse1: one step. block = 32 nodes x 64 cols (head). (proven R3)
// ---------------------------------------------------------------------------
__global__ __launch_bounds__(256)
void diffuse1(const float* __restrict__ hin, const float* __restrict__ v,
              const float* __restrict__ P, float* __restrict__ hout)
{
    const int i0 = blockIdx.x * 32;
    const int h  = blockIdx.y;
    const int tid = threadIdx.x;
    __shared__ float hs[96 * 64];
    __shared__ float ps[32 * NOFF];

    for (int e = tid; e < 96 * 16; e += 256) {
        int lr = e >> 4, c4 = e & 15;
        int j = i0 - WH + lr;
        int jc = min(max(j, 0), S_LEN - 1);
        *(float4*)(hs + lr * 64 + c4 * 4) =
            *(const float4*)(hin + (size_t)jc * E_DIM + h * 64 + c4 * 4);
    }
    for (int e = tid; e < 32 * NOFF; e += 256) {
        int mr = e / NOFF, o = e - mr * NOFF;
        ps[e] = P[(size_t)(i0 + mr) * PROW + h * NOFF + o];
    }
    __syncthreads();

    const int c4 = (tid & 15) * 4;
    const int ci = tid & 15;
    const int g  = tid >> 4;           // 16 groups x 2 out-rows
    const int ob = g * 2;
    const float4* h4 = (const float4*)hs;

    float4 a0 = {0,0,0,0}, a1 = a0;
    for (int lr = ob; lr < ob + 66; ++lr) {
        float4 hval = h4[lr * 16 + ci];
        int o0 = lr - ob;
        if ((unsigned)o0 <= 64u) {
            float p = ps[(ob + 0) * NOFF + o0];
            a0.x += p * hval.x; a0.y += p * hval.y; a0.z += p * hval.z; a0.w += p * hval.w;
        }
        int o1 = o0 - 1;
        if ((unsigned)o1 <= 64u) {
            float p = ps[(ob + 1) * NOFF + o1];
            a1.x += p * hval.x; a1.y += p * hval.y; a1.z += p * hval.z; a1.w += p * hval.w;
        }
    }
#pragma unroll
    for (int r = 0; r < 2; ++r) {
        float4 a = (r == 0) ? a0 : a1;
        size_t base = (size_t)(i0 + ob + r) * E_DIM + h * 64 + c4;
        float4 vv = *(const float4*)(v + base);
        float4 o;
        o.x = 0.9f * a.x + 0.1f * vv.x;
        o.y = 0.9f * a.y + 0.1f * vv.y;
        o.z = 0.9f * a.z + 0.1f * vv.z;
        o.w = 0.9f * a.w + 0.1f * vv.w;
        *(float4*)(hout + base) = o;
    }
}

// ---------------------------------------------------------------------------
// oln v2 (proven R4): y = h@Wo + bo + x, then LayerNorm, fused.
// Block = 16 rows x 512 cols, 512 threads (8 waves x 4 n-tiles). 128 blocks.
// ---------------------------------------------------------------------------
__global__ __launch_bounds__(512)
void oln(const float* __restrict__ hsrc, const float* __restrict__ Wo,
         const float* __restrict__ bo, const float* __restrict__ x,
         const float* __restrict__ g, const float* __restrict__ lb,
         float* __restrict__ out)
{
    __shared__ unsigned short As[16 * 40];
    __shared__ unsigned short Bs[512 * 40];
    __shared__ float rsum[8][16], rsq[8][16];
    const int tid = threadIdx.x;
    const int lane = tid & 63, wave = tid >> 6;   // 8 waves
    const int quad = lane >> 4, l16 = lane & 15;
    const int m0 = blockIdx.x * 16;
    const int n = tid;                            // B staging column

    f32x4 acc[4];
#pragma unroll
    for (int t = 0; t < 4; ++t) acc[t] = (f32x4){0.f,0.f,0.f,0.f};

    for (int kk = 0; kk < E_DIM; kk += 32) {
        float4 av;
        if (tid < 128)
            av = *(const float4*)(hsrc + (size_t)(m0 + (tid >> 3)) * E_DIM + kk + (tid & 7) * 4);
        float bcol[32];
#pragma unroll
        for (int j = 0; j < 32; ++j)
            bcol[j] = Wo[(size_t)(kk + j) * E_DIM + n];
        __syncthreads();
        if (tid < 128) {
            uint2 ap; ap.x = pk2(av.x, av.y); ap.y = pk2(av.z, av.w);
            *(uint2*)(As + (tid >> 3) * 40 + (tid & 7) * 4) = ap;
        }
#pragma unroll
        for (int t = 0; t < 4; ++t) {
            uint4 bp;
            bp.x = pk2(bcol[t*8+0], bcol[t*8+1]); bp.y = pk2(bcol[t*8+2], bcol[t*8+3]);
            bp.z = pk2(bcol[t*8+4], bcol[t*8+5]); bp.w = pk2(bcol[t*8+6], bcol[t*8+7]);
            *(uint4*)(Bs + n * 40 + t * 8) = bp;
        }
        __syncthreads();
        short8 fa = *(const short8*)(As + l16 * 40 + quad * 8);
#pragma unroll
        for (int nt = 0; nt < 4; ++nt) {
            short8 fb = *(const short8*)(Bs + (wave * 64 + nt * 16 + l16) * 40 + quad * 8);
            acc[nt] = __builtin_amdgcn_mfma_f32_16x16x32_bf16(fa, fb, acc[nt], 0, 0, 0);
        }
    }

    // epilogue: bias + resid, LN stats
    float s[4] = {0.f,0.f,0.f,0.f}, s2[4] = {0.f,0.f,0.f,0.f};
#pragma unroll
    for (int nt = 0; nt < 4; ++nt) {
        int nc = wave * 64 + nt * 16 + l16;
        float bv = bo[nc];
#pragma unroll
        for (int r = 0; r < 4; ++r) {
            int m = m0 + quad * 4 + r;
            float vl = acc[nt][r] + bv + x[(size_t)m * E_DIM + nc];
            acc[nt][r] = vl;
            s[r] += vl; s2[r] += vl * vl;
        }
    }
#pragma unroll
    for (int o = 1; o < 16; o <<= 1) {
#pragma unroll
        for (int r = 0; r < 4; ++r) {
            s[r]  += __shfl_xor(s[r], o, 64);
            s2[r] += __shfl_xor(s2[r], o, 64);
        }
    }
    if (l16 == 0) {
#pragma unroll
        for (int r = 0; r < 4; ++r) {
            rsum[wave][quad * 4 + r] = s[r];
            rsq[wave][quad * 4 + r]  = s2[r];
        }
    }
    __syncthreads();
    float mu[4], rs[4];
#pragma unroll
    for (int r = 0; r < 4; ++r) {
        int rl = quad * 4 + r;
        float tot = 0.f, tot2 = 0.f;
#pragma unroll
        for (int w = 0; w < 8; ++w) { tot += rsum[w][rl]; tot2 += rsq[w][rl]; }
        float m_ = tot * (1.f / 512.f);
        float var = tot2 * (1.f / 512.f) - m_ * m_;
        mu[r] = m_; rs[r] = rsqrtf(var + 1e-12f);
    }
#pragma unroll
    for (int nt = 0; nt < 4; ++nt) {
        int nc = wave * 64 + nt * 16 + l16;
        float gv = g[nc], bbv = lb[nc];
#pragma unroll
        for (int r = 0; r < 4; ++r) {
            int m = m0 + quad * 4 + r;
            out[(size_t)m * E_DIM + nc] = (acc[nt][r] - mu[r]) * rs[r] * gv + bbv;
        }
    }
}

// ---------------------------------------------------------------------------
extern "C" void kernel_launch(void* const* d_in, const int* in_sizes, int n_in,
                              void* d_out, int out_size, void* d_ws, size_t ws_size,
                              hipStream_t stream)
{
    const float* x     = (const float*)d_in[0];
    const float* amask = (const float*)d_in[1];
    const float* Wq = (const float*)d_in[4];
    const float* bq = (const float*)d_in[5];
    const float* Wk = (const float*)d_in[6];
    const float* bk = (const float*)d_in[7];
    const float* Wv = (const float*)d_in[8];
    const float* bv = (const float*)d_in[9];
    const float* Wo = (const float*)d_in[10];
    const float* bo = (const float*)d_in[11];
    const float* lng = (const float*)d_in[12];
    const float* lnb = (const float*)d_in[13];
    float* out = (float*)d_out;

    float* ws = (float*)d_ws;
    float* q  = ws;
    float* k  = ws + (size_t)NE;
    float* v  = ws + (size_t)2 * NE;
    float* P  = ws + (size_t)3 * NE;
    float* hA = ws + (size_t)3 * NE + PN;
    float* hB = hA + (size_t)NE;

    qkv_gemm<<<dim3(8, 32, 3), 256, 0, stream>>>(x, Wq, bq, Wk, bk, Wv, bv, q, k, v);

    scores_kernel<<<dim3(64, 8), 256, 0, stream>>>(q, k, amask, P);

    diffuse2<<<dim3(32, 8), 512, 0, stream>>>(v,  v, P, hA);   // steps 1-2
    diffuse2<<<dim3(32, 8), 512, 0, stream>>>(hA, v, P, hB);   // steps 3-4
    diffuse1<<<dim3(64, 8), 256, 0, stream>>>(hB, v, P, hA);   // step 5

    oln<<<128, 512, 0, stream>>>(hA, Wo, bo, x, lng, lnb, out);
}